// Round 15
// baseline (88.376 us; speedup 1.0000x reference)
//
#include <hip/hip_runtime.h>

#define HIDDEN 128

typedef _Float16 f16x8 __attribute__((ext_vector_type(8)));
typedef _Float16 f16x4 __attribute__((ext_vector_type(4)));
typedef _Float16 f16x2 __attribute__((ext_vector_type(2)));
typedef __fp16   fp16v2 __attribute__((ext_vector_type(2)));  // builtin ABI type
typedef float f32x4 __attribute__((ext_vector_type(4)));

// ---------------------------------------------------------------------------
// Kernel 0: pack W1 (fp32, (256,128)) into fp16 MFMA fragments.
// Bmat (K=128, N=256): Bmat[k][n] = n<128 ? W1[k][n] : W1[128+k][n-128]
// Wpk[((jt*4+kt)*64 + lane)*8 + j] = Bmat[kt*32+(lane>>4)*8+j][jt*16+(lane&15)]
// Serves as A-operand fragment (A = Bmat^T): lane holds A[lane&15][(lane>>4)*8+j].
// ---------------------------------------------------------------------------
__global__ __launch_bounds__(64) void prep_w(const float* __restrict__ W1,
                                             _Float16* __restrict__ Wpk) {
  const int blk = blockIdx.x;        // 0..63 = jt*4 + kt
  const int jt = blk >> 2;
  const int kt = blk & 3;
  const int lane = threadIdx.x;      // 0..63
  const int col = jt * 16 + (lane & 15);         // feature 0..255
  const int kbase = kt * 32 + (lane >> 4) * 8;   // 0..120
  f16x8 v;
#pragma unroll
  for (int j = 0; j < 8; ++j) {
    const int k = kbase + j;
    const float w = (col < HIDDEN) ? W1[k * HIDDEN + col]
                                   : W1[(HIDDEN + k) * HIDDEN + (col - HIDDEN)];
    v[j] = (_Float16)w;
  }
  *reinterpret_cast<f16x8*>(Wpk + ((size_t)blk * 64 + lane) * 8) = v;
}

// ---------------------------------------------------------------------------
// Kernel 1 (v12): v11 extended to 4 tiles/block (128 nodes). wfrag/binit
// amortized 4x; all 4 stage-load batches issued up front. Same proven
// barrier pattern per tile: {CVT_SW; bar; COMPUTE_OBUF; bar; COPYOUT}.
// No min-waves launch_bounds (every hint so far caused spills).
// ---------------------------------------------------------------------------
__global__ __launch_bounds__(256) void gemm_mfma_v12(
    const float* __restrict__ h, const _Float16* __restrict__ Wpk,
    const float* __restrict__ b1, _Float16* __restrict__ Af,
    _Float16* __restrict__ Bf, int n_nodes) {
  __shared__ __align__(16) char stage[32 * 256];   // fp16 h-tile, swizzled
  __shared__ __align__(16) char obuf[32 * 528];    // output bounce

  const int tid = threadIdx.x;
  const int lane = tid & 63;
  const int wave = tid >> 6;
  const int nl = lane & 15;
  const int kgrp = lane >> 4;
  const int jt0 = wave * 4;
  const int node0 = blockIdx.x * 128;

  const f16x8* wp = reinterpret_cast<const f16x8*>(Wpk);
  f16x8 wfrag[4][4];
#pragma unroll
  for (int j4 = 0; j4 < 4; ++j4)
#pragma unroll
    for (int kt = 0; kt < 4; ++kt)
      wfrag[j4][kt] = wp[((jt0 + j4) * 4 + kt) * 64 + lane];

  f32x4 binit[4];
#pragma unroll
  for (int j4 = 0; j4 < 4; ++j4) {
    const int jt = jt0 + j4;
    if (jt < 8) {
      binit[j4] = *reinterpret_cast<const f32x4*>(b1 + jt * 16 + kgrp * 4);
    } else {
      binit[j4][0] = 0.f; binit[j4][1] = 0.f; binit[j4][2] = 0.f; binit[j4][3] = 0.f;
    }
  }

  auto STAGELOAD = [&](float4* sbuf, int base) {
#pragma unroll
    for (int q = 0; q < 4; ++q) {
      const int lin = q * 2048 + tid * 8;
      int node = base + (lin >> 8);
      if (node >= n_nodes) node = n_nodes - 1;  // clamp; stores guarded
      sbuf[q] = *reinterpret_cast<const float4*>(
          reinterpret_cast<const char*>(h) + (size_t)node * 512 + (lin & 255) * 2);
    }
  };

  auto CVT_SW = [&](const float4* sbuf) {
#pragma unroll
    for (int q = 0; q < 4; ++q) {
      const int lin = q * 2048 + tid * 8;
      const int row = lin >> 8;
      const int col = lin & 255;
      const fp16v2 p0 = __builtin_amdgcn_cvt_pkrtz(sbuf[q].x, sbuf[q].y);
      const fp16v2 p1 = __builtin_amdgcn_cvt_pkrtz(sbuf[q].z, sbuf[q].w);
      f16x4 v;
      v[0] = (_Float16)p0[0]; v[1] = (_Float16)p0[1];
      v[2] = (_Float16)p1[0]; v[3] = (_Float16)p1[1];
      const int dst = row * 256 + (col ^ ((row & 7) << 4));
      *reinterpret_cast<f16x4*>(stage + dst) = v;
    }
  };

  auto COMPUTE_OBUF = [&]() {
    f32x4 acc[2][4];
#pragma unroll
    for (int s = 0; s < 2; ++s)
#pragma unroll
      for (int j4 = 0; j4 < 4; ++j4) acc[s][j4] = binit[j4];
#pragma unroll
    for (int s = 0; s < 2; ++s) {
      const int row = s * 16 + nl;
#pragma unroll
      for (int kt = 0; kt < 4; ++kt) {
        const int addr = row * 256 + ((kt * 64 + kgrp * 16) ^ ((row & 7) << 4));
        const f16x8 hf = *reinterpret_cast<const f16x8*>(stage + addr);
#pragma unroll
        for (int j4 = 0; j4 < 4; ++j4)
          acc[s][j4] = __builtin_amdgcn_mfma_f32_16x16x32_f16(
              wfrag[j4][kt], hf, acc[s][j4], 0, 0, 0);
      }
    }
#pragma unroll
    for (int s = 0; s < 2; ++s) {
      const int row = s * 16 + nl;
#pragma unroll
      for (int j4 = 0; j4 < 4; ++j4) {
        const int jt = jt0 + j4;
        const int byte = row * 528 + ((jt & 7) * 16 + kgrp * 4) * 2 +
                         ((jt >= 8) ? 256 : 0);
        f16x4 v;
        v[0] = (_Float16)acc[s][j4][0];
        v[1] = (_Float16)acc[s][j4][1];
        v[2] = (_Float16)acc[s][j4][2];
        v[3] = (_Float16)acc[s][j4][3];
        *reinterpret_cast<f16x4*>(obuf + byte) = v;
      }
    }
  };

  const int cs = tid >> 4;
  const int seg = tid & 15;
  auto COPYOUT = [&](int base) {
#pragma unroll
    for (int half = 0; half < 2; ++half) {
      const int cn = half * 16 + cs;
      const int node = base + cn;
      if (node < n_nodes) {
        const f16x8 a = *reinterpret_cast<const f16x8*>(obuf + cn * 528 + seg * 16);
        const f16x8 b = *reinterpret_cast<const f16x8*>(obuf + cn * 528 + 256 + seg * 16);
        *reinterpret_cast<f16x8*>(Af + (size_t)node * HIDDEN + seg * 8) = a;
        *reinterpret_cast<f16x8*>(Bf + (size_t)node * HIDDEN + seg * 8) = b;
      }
    }
  };

  float4 sbuf0[4], sbuf1[4], sbuf2[4], sbuf3[4];
  STAGELOAD(sbuf0, node0);
  STAGELOAD(sbuf1, node0 + 32);
  STAGELOAD(sbuf2, node0 + 64);
  STAGELOAD(sbuf3, node0 + 96);

  // tile 0
  CVT_SW(sbuf0);
  __syncthreads();                 // stage ready
  COMPUTE_OBUF();
  __syncthreads();                 // obuf ready; stage reads done
  COPYOUT(node0);
  // tile 1
  CVT_SW(sbuf1);                   // stage rewrite safe (reads done)
  __syncthreads();                 // stage ready; copyout-0 obuf reads done
  COMPUTE_OBUF();
  __syncthreads();
  COPYOUT(node0 + 32);
  // tile 2
  CVT_SW(sbuf2);
  __syncthreads();
  COMPUTE_OBUF();
  __syncthreads();
  COPYOUT(node0 + 64);
  // tile 3
  CVT_SW(sbuf3);
  __syncthreads();
  COMPUTE_OBUF();
  __syncthreads();
  COPYOUT(node0 + 96);
}

// ---------------------------------------------------------------------------
// Kernel 2 (v7): v5 body (proven stable twice) with ONE change — the row
// gathers use __builtin_nontemporal_load to bypass L1. Theory: the gather is
// 100% L1-miss by construction; per-CU L1 MSHR capacity (~64 misses x ~350cy
// = 5.5 cy/line observed) is the limiter, not L3 bandwidth. NT loads queue
// in the deeper TCC machinery instead.
// ---------------------------------------------------------------------------
__global__ __launch_bounds__(256) void edge_score_v7(
    const int* __restrict__ ei, const _Float16* __restrict__ Af,
    const _Float16* __restrict__ Bf, const float* __restrict__ W2,
    const float* __restrict__ b2, float* __restrict__ out, int n_edges) {
  const int wid = (int)((blockIdx.x * 256 + threadIdx.x) >> 6);
  const int lane = threadIdx.x & 63;
  const int e0 = wid * 16;
  if (e0 >= n_edges) return;

  int srcs[16], dsts[16];
  if (e0 + 16 <= n_edges) {
    const int4* sp = reinterpret_cast<const int4*>(ei + e0);
    const int4* dp = reinterpret_cast<const int4*>(ei + n_edges + e0);
#pragma unroll
    for (int q = 0; q < 4; ++q) {
      const int4 s4 = sp[q], d4 = dp[q];
      srcs[q * 4] = s4.x; srcs[q * 4 + 1] = s4.y; srcs[q * 4 + 2] = s4.z; srcs[q * 4 + 3] = s4.w;
      dsts[q * 4] = d4.x; dsts[q * 4 + 1] = d4.y; dsts[q * 4 + 2] = d4.z; dsts[q * 4 + 3] = d4.w;
    }
  } else {
#pragma unroll
    for (int k = 0; k < 16; ++k) {
      const int e = (e0 + k < n_edges) ? e0 + k : n_edges - 1;
      srcs[k] = ei[e];
      dsts[k] = ei[n_edges + e];
    }
  }

  const char* Afc = (const char*)Af;
  const char* Bfc = (const char*)Bf;
  const unsigned int loff = (unsigned int)(lane << 2);

  f16x2 av[16], bv[16];
#pragma unroll
  for (int k = 0; k < 16; ++k) {
    av[k] = __builtin_nontemporal_load(
        reinterpret_cast<const f16x2*>(Afc + (((unsigned int)srcs[k] << 8) + loff)));
    bv[k] = __builtin_nontemporal_load(
        reinterpret_cast<const f16x2*>(Bfc + (((unsigned int)dsts[k] << 8) + loff)));
  }

  const float2 w2v = reinterpret_cast<const float2*>(W2)[lane];
  const fp16v2 w2h = __builtin_amdgcn_cvt_pkrtz(w2v.x, w2v.y);
  const _Float16 h0 = (_Float16)0.f;

  float p[16];
#pragma unroll
  for (int k = 0; k < 16; ++k) {
    f16x2 s = av[k] + bv[k];                 // v_pk_add_f16
    s[0] = s[0] > h0 ? s[0] : h0;            // pk max vs 0
    s[1] = s[1] > h0 ? s[1] : h0;
    p[k] = __builtin_amdgcn_fdot2(__builtin_bit_cast(fp16v2, s), w2h, 0.f, false);
  }

  auto mrg = [&](float a, float b, int off) {
    const float as = a + __shfl_xor(a, off, 64);
    const float bs = b + __shfl_xor(b, off, 64);
    return (lane & off) ? bs : as;
  };
  float q[8];
#pragma unroll
  for (int i = 0; i < 8; ++i) q[i] = mrg(p[2 * i], p[2 * i + 1], 1);
  float r[4];
#pragma unroll
  for (int i = 0; i < 4; ++i) r[i] = mrg(q[2 * i], q[2 * i + 1], 2);
  float s2[2];
#pragma unroll
  for (int i = 0; i < 2; ++i) s2[i] = mrg(r[2 * i], r[2 * i + 1], 4);
  float t = mrg(s2[0], s2[1], 8);
  t += __shfl_xor(t, 16, 64);
  t += __shfl_xor(t, 32, 64);

  if (lane < 16 && e0 + lane < n_edges) out[e0 + lane] = t + b2[0];
}

// ---------------------------------------------------------------------------
// Fallback (ws too small): fused fp32 per-edge compute.
// ---------------------------------------------------------------------------
__global__ __launch_bounds__(256) void fused_fallback(
    const float* __restrict__ h, const int* __restrict__ ei,
    const float* __restrict__ W1, const float* __restrict__ b1,
    const float* __restrict__ W2, const float* __restrict__ b2,
    float* __restrict__ out, int n_edges) {
  const int e = (int)((blockIdx.x * 256 + threadIdx.x) >> 6);
  const int lane = threadIdx.x & 63;
  if (e >= n_edges) return;
  const int src = ei[e], dst = ei[n_edges + e];
  const float* hs = h + (size_t)src * HIDDEN;
  const float* hd = h + (size_t)dst * HIDDEN;
  float acc0 = b1[lane], acc1 = b1[lane + 64];
  for (int k = 0; k < HIDDEN; ++k) {
    const float s = hs[k], d = hd[k];
    acc0 = fmaf(s, W1[k * HIDDEN + lane], acc0);
    acc0 = fmaf(d, W1[(k + HIDDEN) * HIDDEN + lane], acc0);
    acc1 = fmaf(s, W1[k * HIDDEN + lane + 64], acc1);
    acc1 = fmaf(d, W1[(k + HIDDEN) * HIDDEN + lane + 64], acc1);
  }
  acc0 = acc0 > 0.f ? acc0 : 0.f;
  acc1 = acc1 > 0.f ? acc1 : 0.f;
  float p = fmaf(acc0, W2[lane], acc1 * W2[lane + 64]);
#pragma unroll
  for (int off = 32; off >= 1; off >>= 1) p += __shfl_down(p, off, 64);
  if (lane == 0) out[e] = p + b2[0];
}

extern "C" void kernel_launch(void* const* d_in, const int* in_sizes, int n_in,
                              void* d_out, int out_size, void* d_ws, size_t ws_size,
                              hipStream_t stream) {
  const float* h  = (const float*)d_in[0];
  const int*   ei = (const int*)d_in[1];
  const float* W1 = (const float*)d_in[2];
  const float* b1 = (const float*)d_in[3];
  const float* W2 = (const float*)d_in[4];
  const float* b2 = (const float*)d_in[5];
  float* out = (float*)d_out;

  const int n_nodes = in_sizes[0] / HIDDEN;  // 100000
  const int n_edges = in_sizes[1] / 2;       // 640000

  const size_t wpk_halfs  = 64 * 64 * 8;                       // 32768
  const size_t proj_halfs = (size_t)n_nodes * HIDDEN;          // 12.8M
  const size_t need = (wpk_halfs + 2 * proj_halfs) * sizeof(_Float16);

  if (ws_size >= need) {
    _Float16* Wpk = (_Float16*)d_ws;
    _Float16* A   = Wpk + wpk_halfs;
    _Float16* B   = A + proj_halfs;

    prep_w<<<64, 64, 0, stream>>>(W1, Wpk);

    const int gblocks = (n_nodes + 127) / 128;    // 782
    gemm_mfma_v12<<<gblocks, 256, 0, stream>>>(h, Wpk, b1, A, B, n_nodes);

    const int nwaves = (n_edges + 15) / 16;
    const int eblocks = (nwaves + 3) / 4;
    edge_score_v7<<<eblocks, 256, 0, stream>>>(ei, A, B, W2, b2, out, n_edges);
  } else {
    const int eblocks = (n_edges + 3) / 4;
    fused_fallback<<<eblocks, 256, 0, stream>>>(h, ei, W1, b1, W2, b2, out, n_edges);
  }
}

// Round 16
// 75.729 us; speedup vs baseline: 1.1670x; 1.1670x over previous
//
#include <hip/hip_runtime.h>

#define HIDDEN 128

typedef _Float16 f16x8 __attribute__((ext_vector_type(8)));
typedef _Float16 f16x4 __attribute__((ext_vector_type(4)));
typedef _Float16 f16x2 __attribute__((ext_vector_type(2)));
typedef __fp16   fp16v2 __attribute__((ext_vector_type(2)));  // builtin ABI type
typedef float f32x4 __attribute__((ext_vector_type(4)));

// ---------------------------------------------------------------------------
// Kernel 0: pack W1 (fp32, (256,128)) into fp16 MFMA fragments.
// Bmat (K=128, N=256): Bmat[k][n] = n<128 ? W1[k][n] : W1[128+k][n-128]
// Wpk[((jt*4+kt)*64 + lane)*8 + j] = Bmat[kt*32+(lane>>4)*8+j][jt*16+(lane&15)]
// Serves as A-operand fragment (A = Bmat^T): lane holds A[lane&15][(lane>>4)*8+j].
// ---------------------------------------------------------------------------
__global__ __launch_bounds__(64) void prep_w(const float* __restrict__ W1,
                                             _Float16* __restrict__ Wpk) {
  const int blk = blockIdx.x;        // 0..63 = jt*4 + kt
  const int jt = blk >> 2;
  const int kt = blk & 3;
  const int lane = threadIdx.x;      // 0..63
  const int col = jt * 16 + (lane & 15);         // feature 0..255
  const int kbase = kt * 32 + (lane >> 4) * 8;   // 0..120
  f16x8 v;
#pragma unroll
  for (int j = 0; j < 8; ++j) {
    const int k = kbase + j;
    const float w = (col < HIDDEN) ? W1[k * HIDDEN + col]
                                   : W1[(HIDDEN + k) * HIDDEN + (col - HIDDEN)];
    v[j] = (_Float16)w;
  }
  *reinterpret_cast<f16x8*>(Wpk + ((size_t)blk * 64 + lane) * 8) = v;
}

// ---------------------------------------------------------------------------
// Kernel 1 (v12, unchanged — best measured at ~23.6us): 4 tiles/block
// (128 nodes), wfrag/binit amortized 4x, all 4 stage-load batches issued up
// front (one combined L3/HBM latency), canonical dense-load + swizzled-LDS
// + ds_read_b128 + LDS-bounce epilogue. ~4.3 TB/s effective on 102 MB
// round-trip — near the mixed-stream ceiling with conversion in the path.
// ---------------------------------------------------------------------------
__global__ __launch_bounds__(256) void gemm_mfma_v12(
    const float* __restrict__ h, const _Float16* __restrict__ Wpk,
    const float* __restrict__ b1, _Float16* __restrict__ Af,
    _Float16* __restrict__ Bf, int n_nodes) {
  __shared__ __align__(16) char stage[32 * 256];   // fp16 h-tile, swizzled
  __shared__ __align__(16) char obuf[32 * 528];    // output bounce

  const int tid = threadIdx.x;
  const int lane = tid & 63;
  const int wave = tid >> 6;
  const int nl = lane & 15;
  const int kgrp = lane >> 4;
  const int jt0 = wave * 4;
  const int node0 = blockIdx.x * 128;

  const f16x8* wp = reinterpret_cast<const f16x8*>(Wpk);
  f16x8 wfrag[4][4];
#pragma unroll
  for (int j4 = 0; j4 < 4; ++j4)
#pragma unroll
    for (int kt = 0; kt < 4; ++kt)
      wfrag[j4][kt] = wp[((jt0 + j4) * 4 + kt) * 64 + lane];

  f32x4 binit[4];
#pragma unroll
  for (int j4 = 0; j4 < 4; ++j4) {
    const int jt = jt0 + j4;
    if (jt < 8) {
      binit[j4] = *reinterpret_cast<const f32x4*>(b1 + jt * 16 + kgrp * 4);
    } else {
      binit[j4][0] = 0.f; binit[j4][1] = 0.f; binit[j4][2] = 0.f; binit[j4][3] = 0.f;
    }
  }

  auto STAGELOAD = [&](float4* sbuf, int base) {
#pragma unroll
    for (int q = 0; q < 4; ++q) {
      const int lin = q * 2048 + tid * 8;
      int node = base + (lin >> 8);
      if (node >= n_nodes) node = n_nodes - 1;  // clamp; stores guarded
      sbuf[q] = *reinterpret_cast<const float4*>(
          reinterpret_cast<const char*>(h) + (size_t)node * 512 + (lin & 255) * 2);
    }
  };

  auto CVT_SW = [&](const float4* sbuf) {
#pragma unroll
    for (int q = 0; q < 4; ++q) {
      const int lin = q * 2048 + tid * 8;
      const int row = lin >> 8;
      const int col = lin & 255;
      const fp16v2 p0 = __builtin_amdgcn_cvt_pkrtz(sbuf[q].x, sbuf[q].y);
      const fp16v2 p1 = __builtin_amdgcn_cvt_pkrtz(sbuf[q].z, sbuf[q].w);
      f16x4 v;
      v[0] = (_Float16)p0[0]; v[1] = (_Float16)p0[1];
      v[2] = (_Float16)p1[0]; v[3] = (_Float16)p1[1];
      const int dst = row * 256 + (col ^ ((row & 7) << 4));
      *reinterpret_cast<f16x4*>(stage + dst) = v;
    }
  };

  auto COMPUTE_OBUF = [&]() {
    f32x4 acc[2][4];
#pragma unroll
    for (int s = 0; s < 2; ++s)
#pragma unroll
      for (int j4 = 0; j4 < 4; ++j4) acc[s][j4] = binit[j4];
#pragma unroll
    for (int s = 0; s < 2; ++s) {
      const int row = s * 16 + nl;
#pragma unroll
      for (int kt = 0; kt < 4; ++kt) {
        const int addr = row * 256 + ((kt * 64 + kgrp * 16) ^ ((row & 7) << 4));
        const f16x8 hf = *reinterpret_cast<const f16x8*>(stage + addr);
#pragma unroll
        for (int j4 = 0; j4 < 4; ++j4)
          acc[s][j4] = __builtin_amdgcn_mfma_f32_16x16x32_f16(
              wfrag[j4][kt], hf, acc[s][j4], 0, 0, 0);
      }
    }
#pragma unroll
    for (int s = 0; s < 2; ++s) {
      const int row = s * 16 + nl;
#pragma unroll
      for (int j4 = 0; j4 < 4; ++j4) {
        const int jt = jt0 + j4;
        const int byte = row * 528 + ((jt & 7) * 16 + kgrp * 4) * 2 +
                         ((jt >= 8) ? 256 : 0);
        f16x4 v;
        v[0] = (_Float16)acc[s][j4][0];
        v[1] = (_Float16)acc[s][j4][1];
        v[2] = (_Float16)acc[s][j4][2];
        v[3] = (_Float16)acc[s][j4][3];
        *reinterpret_cast<f16x4*>(obuf + byte) = v;
      }
    }
  };

  const int cs = tid >> 4;
  const int seg = tid & 15;
  auto COPYOUT = [&](int base) {
#pragma unroll
    for (int half = 0; half < 2; ++half) {
      const int cn = half * 16 + cs;
      const int node = base + cn;
      if (node < n_nodes) {
        const f16x8 a = *reinterpret_cast<const f16x8*>(obuf + cn * 528 + seg * 16);
        const f16x8 b = *reinterpret_cast<const f16x8*>(obuf + cn * 528 + 256 + seg * 16);
        *reinterpret_cast<f16x8*>(Af + (size_t)node * HIDDEN + seg * 8) = a;
        *reinterpret_cast<f16x8*>(Bf + (size_t)node * HIDDEN + seg * 8) = b;
      }
    }
  };

  float4 sbuf0[4], sbuf1[4], sbuf2[4], sbuf3[4];
  STAGELOAD(sbuf0, node0);
  STAGELOAD(sbuf1, node0 + 32);
  STAGELOAD(sbuf2, node0 + 64);
  STAGELOAD(sbuf3, node0 + 96);

  // tile 0
  CVT_SW(sbuf0);
  __syncthreads();                 // stage ready
  COMPUTE_OBUF();
  __syncthreads();                 // obuf ready; stage reads done
  COPYOUT(node0);
  // tile 1
  CVT_SW(sbuf1);                   // stage rewrite safe (reads done)
  __syncthreads();                 // stage ready; copyout-0 obuf reads done
  COMPUTE_OBUF();
  __syncthreads();
  COPYOUT(node0 + 32);
  // tile 2
  CVT_SW(sbuf2);
  __syncthreads();
  COMPUTE_OBUF();
  __syncthreads();
  COPYOUT(node0 + 64);
  // tile 3
  CVT_SW(sbuf3);
  __syncthreads();
  COMPUTE_OBUF();
  __syncthreads();
  COPYOUT(node0 + 96);
}

// ---------------------------------------------------------------------------
// Kernel 2 (v5, reverted verbatim — NT-load experiment (v7) was 31% SLOWER:
// the nt flag forfeits L2 caching, which carries ~1/3 of the gather service
// rate. v5 is the proven config: ~46us, schedule-insensitive across three
// structures = cache-hierarchy service ceiling for 5.1M random 64B lines).
// Per edge: score = relu(A[src]+B[dst]).W2 + b2. One wave per 16 edges;
// int4 index loads; packed fp16 add/relu + fdot2; merged butterfly.
// ---------------------------------------------------------------------------
__global__ __launch_bounds__(256) void edge_score_v5(
    const int* __restrict__ ei, const _Float16* __restrict__ Af,
    const _Float16* __restrict__ Bf, const float* __restrict__ W2,
    const float* __restrict__ b2, float* __restrict__ out, int n_edges) {
  const int wid = (int)((blockIdx.x * 256 + threadIdx.x) >> 6);
  const int lane = threadIdx.x & 63;
  const int e0 = wid * 16;
  if (e0 >= n_edges) return;

  int srcs[16], dsts[16];
  if (e0 + 16 <= n_edges) {
    const int4* sp = reinterpret_cast<const int4*>(ei + e0);
    const int4* dp = reinterpret_cast<const int4*>(ei + n_edges + e0);
#pragma unroll
    for (int q = 0; q < 4; ++q) {
      const int4 s4 = sp[q], d4 = dp[q];
      srcs[q * 4] = s4.x; srcs[q * 4 + 1] = s4.y; srcs[q * 4 + 2] = s4.z; srcs[q * 4 + 3] = s4.w;
      dsts[q * 4] = d4.x; dsts[q * 4 + 1] = d4.y; dsts[q * 4 + 2] = d4.z; dsts[q * 4 + 3] = d4.w;
    }
  } else {
#pragma unroll
    for (int k = 0; k < 16; ++k) {
      const int e = (e0 + k < n_edges) ? e0 + k : n_edges - 1;
      srcs[k] = ei[e];
      dsts[k] = ei[n_edges + e];
    }
  }

  const char* Afc = (const char*)Af;
  const char* Bfc = (const char*)Bf;
  const unsigned int loff = (unsigned int)(lane << 2);

  f16x2 av[16], bv[16];
#pragma unroll
  for (int k = 0; k < 16; ++k) {
    av[k] = *reinterpret_cast<const f16x2*>(Afc + (((unsigned int)srcs[k] << 8) + loff));
    bv[k] = *reinterpret_cast<const f16x2*>(Bfc + (((unsigned int)dsts[k] << 8) + loff));
  }

  const float2 w2v = reinterpret_cast<const float2*>(W2)[lane];
  const fp16v2 w2h = __builtin_amdgcn_cvt_pkrtz(w2v.x, w2v.y);
  const _Float16 h0 = (_Float16)0.f;

  float p[16];
#pragma unroll
  for (int k = 0; k < 16; ++k) {
    f16x2 s = av[k] + bv[k];                 // v_pk_add_f16
    s[0] = s[0] > h0 ? s[0] : h0;            // pk max vs 0
    s[1] = s[1] > h0 ? s[1] : h0;
    p[k] = __builtin_amdgcn_fdot2(__builtin_bit_cast(fp16v2, s), w2h, 0.f, false);
  }

  auto mrg = [&](float a, float b, int off) {
    const float as = a + __shfl_xor(a, off, 64);
    const float bs = b + __shfl_xor(b, off, 64);
    return (lane & off) ? bs : as;
  };
  float q[8];
#pragma unroll
  for (int i = 0; i < 8; ++i) q[i] = mrg(p[2 * i], p[2 * i + 1], 1);
  float r[4];
#pragma unroll
  for (int i = 0; i < 4; ++i) r[i] = mrg(q[2 * i], q[2 * i + 1], 2);
  float s2[2];
#pragma unroll
  for (int i = 0; i < 2; ++i) s2[i] = mrg(r[2 * i], r[2 * i + 1], 4);
  float t = mrg(s2[0], s2[1], 8);
  t += __shfl_xor(t, 16, 64);
  t += __shfl_xor(t, 32, 64);

  if (lane < 16 && e0 + lane < n_edges) out[e0 + lane] = t + b2[0];
}

// ---------------------------------------------------------------------------
// Fallback (ws too small): fused fp32 per-edge compute.
// ---------------------------------------------------------------------------
__global__ __launch_bounds__(256) void fused_fallback(
    const float* __restrict__ h, const int* __restrict__ ei,
    const float* __restrict__ W1, const float* __restrict__ b1,
    const float* __restrict__ W2, const float* __restrict__ b2,
    float* __restrict__ out, int n_edges) {
  const int e = (int)((blockIdx.x * 256 + threadIdx.x) >> 6);
  const int lane = threadIdx.x & 63;
  if (e >= n_edges) return;
  const int src = ei[e], dst = ei[n_edges + e];
  const float* hs = h + (size_t)src * HIDDEN;
  const float* hd = h + (size_t)dst * HIDDEN;
  float acc0 = b1[lane], acc1 = b1[lane + 64];
  for (int k = 0; k < HIDDEN; ++k) {
    const float s = hs[k], d = hd[k];
    acc0 = fmaf(s, W1[k * HIDDEN + lane], acc0);
    acc0 = fmaf(d, W1[(k + HIDDEN) * HIDDEN + lane], acc0);
    acc1 = fmaf(s, W1[k * HIDDEN + lane + 64], acc1);
    acc1 = fmaf(d, W1[(k + HIDDEN) * HIDDEN + lane + 64], acc1);
  }
  acc0 = acc0 > 0.f ? acc0 : 0.f;
  acc1 = acc1 > 0.f ? acc1 : 0.f;
  float p = fmaf(acc0, W2[lane], acc1 * W2[lane + 64]);
#pragma unroll
  for (int off = 32; off >= 1; off >>= 1) p += __shfl_down(p, off, 64);
  if (lane == 0) out[e] = p + b2[0];
}

extern "C" void kernel_launch(void* const* d_in, const int* in_sizes, int n_in,
                              void* d_out, int out_size, void* d_ws, size_t ws_size,
                              hipStream_t stream) {
  const float* h  = (const float*)d_in[0];
  const int*   ei = (const int*)d_in[1];
  const float* W1 = (const float*)d_in[2];
  const float* b1 = (const float*)d_in[3];
  const float* W2 = (const float*)d_in[4];
  const float* b2 = (const float*)d_in[5];
  float* out = (float*)d_out;

  const int n_nodes = in_sizes[0] / HIDDEN;  // 100000
  const int n_edges = in_sizes[1] / 2;       // 640000

  const size_t wpk_halfs  = 64 * 64 * 8;                       // 32768
  const size_t proj_halfs = (size_t)n_nodes * HIDDEN;          // 12.8M
  const size_t need = (wpk_halfs + 2 * proj_halfs) * sizeof(_Float16);

  if (ws_size >= need) {
    _Float16* Wpk = (_Float16*)d_ws;
    _Float16* A   = Wpk + wpk_halfs;
    _Float16* B   = A + proj_halfs;

    prep_w<<<64, 64, 0, stream>>>(W1, Wpk);

    const int gblocks = (n_nodes + 127) / 128;    // 782
    gemm_mfma_v12<<<gblocks, 256, 0, stream>>>(h, Wpk, b1, A, B, n_nodes);

    const int nwaves = (n_edges + 15) / 16;
    const int eblocks = (nwaves + 3) / 4;
    edge_score_v5<<<eblocks, 256, 0, stream>>>(ei, A, B, W2, b2, out, n_edges);
  } else {
    const int eblocks = (n_edges + 3) / 4;
    fused_fallback<<<eblocks, 256, 0, stream>>>(h, ei, W1, b1, W2, b2, out, n_edges);
  }
}